// Round 11
// baseline (420.678 us; speedup 1.0000x reference)
//
#include <hip/hip_runtime.h>
#include <hip/hip_bf16.h>

// FNOBlock on MI355X — round 7: barrier-free GEMM loops (B direct global->VGPR from L2),
// one-shot A/H3 LDS builds (2 barriers total), 64-v FFT blocks for 256B DRAM segments.
//   d_out (134 MB) holds packed bf16 complex planes (uint32) between IFFT stages,
//   overwritten in-place by the final real fp32 output.

typedef unsigned short ushort_t;
typedef unsigned int   uint_t;
typedef __attribute__((ext_vector_type(8))) short short8b;   // 8 x bf16
typedef __attribute__((ext_vector_type(4))) float f32x4;

__device__ __forceinline__ uint_t packf2(float lo, float hi){
  union { __hip_bfloat162 h; uint_t u; } v;
  v.h = __float22bfloat162_rn(make_float2(lo, hi));
  return v.u;
}
__device__ __forceinline__ ushort_t f2bf(float f){
  union { __hip_bfloat16 h; ushort_t u; } v;
  v.h = __float2bfloat16(f);
  return v.u;
}
__device__ __forceinline__ float bf_lo(uint_t u){
  union { uint_t u; float f; } v; v.u = u << 16; return v.f;
}
__device__ __forceinline__ float bf_hi(uint_t u){
  union { uint_t u; float f; } v; v.u = u & 0xFFFF0000u; return v.f;
}

// ---------------- register FFTs (inverse sign, DIF, out[p] = X[brev(p)]) ----------------
constexpr int BR16T[16] = {0,8,4,12,2,10,6,14,1,9,5,13,3,11,7,15};
constexpr int BR32T[32] = {0,16,8,24,4,20,12,28,2,18,10,26,6,22,14,30,
                           1,17,9,25,5,21,13,29,3,19,11,27,7,23,15,31};

__device__ __forceinline__ void bfly(float& ar, float& ai, float& br, float& bi,
                                     float wr, float wi){
  float sr = ar - br, si = ai - bi;
  ar += br; ai += bi;
  br = sr*wr - si*wi;
  bi = sr*wi + si*wr;
}

__device__ __forceinline__ void fft16_inv(float* xr, float* xi){
  const float C1 = 0.92387953251128674f, S1 = 0.38268343236508978f,
              C2 = 0.70710678118654752f;
  bfly(xr[0],xi[0],xr[8],xi[8],    1.f, 0.f);
  bfly(xr[1],xi[1],xr[9],xi[9],    C1,  S1);
  bfly(xr[2],xi[2],xr[10],xi[10],  C2,  C2);
  bfly(xr[3],xi[3],xr[11],xi[11],  S1,  C1);
  bfly(xr[4],xi[4],xr[12],xi[12],  0.f, 1.f);
  bfly(xr[5],xi[5],xr[13],xi[13], -S1,  C1);
  bfly(xr[6],xi[6],xr[14],xi[14], -C2,  C2);
  bfly(xr[7],xi[7],xr[15],xi[15], -C1,  S1);
  #pragma unroll
  for (int h = 0; h < 16; h += 8){
    bfly(xr[h+0],xi[h+0],xr[h+4],xi[h+4],  1.f, 0.f);
    bfly(xr[h+1],xi[h+1],xr[h+5],xi[h+5],  C2,  C2);
    bfly(xr[h+2],xi[h+2],xr[h+6],xi[h+6],  0.f, 1.f);
    bfly(xr[h+3],xi[h+3],xr[h+7],xi[h+7], -C2,  C2);
  }
  #pragma unroll
  for (int h = 0; h < 16; h += 4){
    bfly(xr[h+0],xi[h+0],xr[h+2],xi[h+2], 1.f, 0.f);
    bfly(xr[h+1],xi[h+1],xr[h+3],xi[h+3], 0.f, 1.f);
  }
  #pragma unroll
  for (int h = 0; h < 16; h += 2)
    bfly(xr[h],xi[h],xr[h+1],xi[h+1], 1.f, 0.f);
}

__device__ __forceinline__ void fft32_inv(float* xr, float* xi){
  constexpr float WR[16] = {
    1.f, 0.98078528040323044f, 0.92387953251128674f, 0.83146961230254524f,
    0.70710678118654752f, 0.55557023301960222f, 0.38268343236508978f, 0.19509032201612827f,
    0.f,-0.19509032201612827f,-0.38268343236508978f,-0.55557023301960222f,
   -0.70710678118654752f,-0.83146961230254524f,-0.92387953251128674f,-0.98078528040323044f};
  constexpr float WI[16] = {
    0.f, 0.19509032201612827f, 0.38268343236508978f, 0.55557023301960222f,
    0.70710678118654752f, 0.83146961230254524f, 0.92387953251128674f, 0.98078528040323044f,
    1.f, 0.98078528040323044f, 0.92387953251128674f, 0.83146961230254524f,
    0.70710678118654752f, 0.55557023301960222f, 0.38268343236508978f, 0.19509032201612827f};
  #pragma unroll
  for (int j = 0; j < 16; ++j)
    bfly(xr[j],xi[j],xr[j+16],xi[j+16], WR[j], WI[j]);
  fft16_inv(xr, xi);
  fft16_inv(xr+16, xi+16);
}

// ---------------- tables ----------------
__global__ void fill_tables(float2* t256f, float2* t256i, float2* t512f, float2* t512i){
  int i = threadIdx.x;              // 512 threads
  const double PI2 = 6.283185307179586476925286766559;
  if (i < 256){
    double a = PI2 * (double)i / 256.0;
    float c = (float)cos(a), s = (float)sin(a);
    t256f[i] = make_float2(c, -s);
    t256i[i] = make_float2(c,  s);
  }
  {
    double a = PI2 * (double)i / 512.0;
    float c = (float)cos(a), s = (float)sin(a);
    t512f[i] = make_float2(c, -s);
    t512i[i] = make_float2(c,  s);
  }
}

// ---------------- forward fft2 of x (naive DFTs, tiny) ----------------
__global__ void dft_m(const float* __restrict__ x, float2* __restrict__ Yw,
                      const float2* __restrict__ twf){
  __shared__ float xs[256];
  __shared__ float2 tws[256];
  int b = blockIdx.x, k = threadIdx.x;
  xs[k]  = x[b*256 + k];
  tws[k] = twf[k];
  __syncthreads();
  float yr = 0.f, yi = 0.f;
  for (int m = 0; m < 256; ++m){
    float2 w = tws[(m*k) & 255];
    float xv = xs[m];
    yr += xv*w.x; yi += xv*w.y;
  }
  Yw[b*256 + k] = make_float2(yr, yi);
}

__global__ void dft_b(const float2* __restrict__ Yw, float* __restrict__ Xr,
                      float* __restrict__ Xi, const float2* __restrict__ twf){
  __shared__ float2 tws[512];
  int j = blockIdx.x, k = threadIdx.x;
  tws[k]       = twf[k];
  tws[k + 256] = twf[k + 256];
  __syncthreads();
  float xr = 0.f, xi = 0.f;
  for (int b = 0; b < 512; ++b){
    float2 y = Yw[b*256 + k];
    float2 w = tws[(b*j) & 511];
    xr += y.x*w.x - y.y*w.y;
    xi += y.x*w.y + y.y*w.x;
  }
  Xr[j*256 + k] = xr;
  Xi[j*256 + k] = xi;
}

// ---------------- weight prep ----------------
// Wct[u][t] = sum_v lin1_w[u][v]*w1[t][v]  (bf16)
__global__ void prep_w(const float* __restrict__ w1, const float* __restrict__ lin1_w,
                       ushort_t* __restrict__ Wct){
  __shared__ float l1[256];
  int u = blockIdx.x, t = threadIdx.x;
  l1[t] = lin1_w[u*256 + t];
  __syncthreads();
  float s = 0.f;
  for (int v = 0; v < 256; ++v)
    s += l1[v] * w1[t*256 + v];
  Wct[u*256 + t] = f2bf(s);
}

// M[k][v] = sum_u lin2_w[u][k] * e^{2pi i uv/256}/256 ; Bt*[v][k] = M[k][v]
__global__ void prep_g(const float* __restrict__ lin2_w, const float2* __restrict__ ph,
                       ushort_t* __restrict__ BtR, ushort_t* __restrict__ BtI){
  int v = blockIdx.x, k = threadIdx.x;
  float cre = 0.f, cim = 0.f;
  for (int u = 0; u < 256; ++u){
    float w = lin2_w[u*256 + k];
    float2 t = ph[(u*v) & 255];
    cre += w*t.x; cim += w*t.y;
  }
  BtR[v*256 + k] = f2bf(cre * (1.f/256.f));
  BtI[v*256 + k] = f2bf(cim * (1.f/256.f));
}

// b2g[v] = sum_u b2[u] * e^{2pi i uv/256}/256
__global__ void prep_b2g(const float* __restrict__ b2, const float2* __restrict__ ph,
                         float2* __restrict__ b2g){
  int v = threadIdx.x;
  float cre = 0.f, cim = 0.f;
  for (int u = 0; u < 256; ++u){
    float w = b2[u];
    float2 t = ph[(u*v) & 255];
    cre += w*t.x; cim += w*t.y;
  }
  b2g[v] = make_float2(cre * (1.f/256.f), cim * (1.f/256.f));
}

// ---------------- fused: h0 build + GEMM1 + GEMM2(+v-IFFT) -> packed planes ----------------
// 512 threads (8 waves), 32 complex rows/block (stacked: [re 0..31][im 32..63]).
// Wave w owns output cols [32w, 32w+32). B fragments load directly from global (L2-hot).
// LDS: At[64][256] bf16 (32K, XOR-swizzled slots) + H3[64][256] bf16 (32K). 2 barriers total.
__global__ __launch_bounds__(512, 4)
void fused_mid(const float* __restrict__ Xr, const float* __restrict__ Xi,
               const float* __restrict__ w0,
               const ushort_t* __restrict__ Wct,
               const ushort_t* __restrict__ BtR, const ushort_t* __restrict__ BtI,
               const float* __restrict__ b1, const float2* __restrict__ b2g,
               const float2* __restrict__ ph,      // e^{+2pi i k/256}
               uint_t* __restrict__ OutP)
{
  __shared__ __align__(16) ushort_t At[64*256];   // 32KB
  __shared__ __align__(16) ushort_t H3[64*256];   // 32KB

  const int tid  = threadIdx.x;
  const int lane = tid & 63;
  const int w8   = tid >> 6;          // wave 0..7
  const int L    = lane & 15;
  const int chk  = lane >> 4;         // 0..3 (k-chunk / C-row-quad)
  const int cq   = chk, cl = L;
  const int cr0  = blockIdx.x * 32;

  // ---------- A-build: all of At[64][256], slots XOR-swizzled by row&7 ----------
  {
    const int arow = tid >> 3;          // stacked row 0..63
    const int ak0  = (tid & 7) * 4;     // k offset within 32-chunk
    const int ajj  = arow & 31;
    const bool aim = arow >= 32;
    const float axr = Xr[cr0 + ajj];
    const float axi = Xi[cr0 + ajj];
    const int am = (cr0 + ajj) & 255;
    const float2 apj = ph[am];
    #pragma unroll
    for (int kt = 0; kt < 8; ++kt){
      const int k = kt*32 + ak0;
      const float4 w4 = *(const float4*)&w0[(size_t)am*256 + k];
      float wv[4] = {w4.x, w4.y, w4.z, w4.w};
      float va[4];
      #pragma unroll
      for (int e = 0; e < 4; ++e){
        float r = fmaxf(axr*wv[e], 0.f);
        float m = fmaxf(axi*wv[e], 0.f);
        va[e] = aim ? (apj.y*r + apj.x*m) : (apj.x*r - apj.y*m);
      }
      int s = (k >> 3) ^ (arow & 7);
      *(uint2*)((char*)At + arow*512 + s*16 + (ak0 & 7)*2) =
          make_uint2(packf2(va[0], va[1]), packf2(va[2], va[3]));
    }
  }
  __syncthreads();

  // ---------- GEMM1: acc = A(64x256) @ Wct^T  (B from global, no barriers) ----------
  f32x4 acc[4][2];
  #pragma unroll
  for (int m = 0; m < 4; ++m)
    #pragma unroll
    for (int n = 0; n < 2; ++n)
      acc[m][n] = (f32x4){0.f,0.f,0.f,0.f};

  #pragma unroll
  for (int kt = 0; kt < 8; ++kt){
    short8b av[4], bv[2];
    #pragma unroll
    for (int n = 0; n < 2; ++n){
      int col = w8*32 + n*16 + L;
      bv[n] = *(const short8b*)&Wct[col*256 + kt*32 + chk*8];
    }
    #pragma unroll
    for (int m = 0; m < 4; ++m){
      int row = m*16 + L;
      av[m] = *(const short8b*)&At[row*256 + (((kt*4 + chk) ^ (L & 7)) << 3)];
    }
    #pragma unroll
    for (int m = 0; m < 4; ++m)
      #pragma unroll
      for (int n = 0; n < 2; ++n)
        acc[m][n] = __builtin_amdgcn_mfma_f32_16x16x32_bf16(av[m], bv[n], acc[m][n], 0,0,0);
  }

  // ---------- epilogue1: h3 = relu(acc + b1(re rows)) -> H3 bf16 (swizzled) ----------
  #pragma unroll
  for (int m = 0; m < 4; ++m){
    #pragma unroll
    for (int n = 0; n < 2; ++n){
      int col = w8*32 + n*16 + cl;
      float badd = (m < 2) ? b1[col] : 0.f;
      #pragma unroll
      for (int q = 0; q < 4; ++q){
        int row = m*16 + cq*4 + q;
        float v = fmaxf(acc[m][n][q] + badd, 0.f);
        int s = (col >> 3) ^ (row & 7);
        H3[row*256 + s*8 + (col & 7)] = f2bf(v);
      }
    }
  }
  __syncthreads();

  // ---------- GEMM2: accR/accI = H3 @ BtR^T / BtI^T  (B from global, no barriers) ----------
  f32x4 accR[4][2], accI[4][2];
  #pragma unroll
  for (int m = 0; m < 4; ++m)
    #pragma unroll
    for (int n = 0; n < 2; ++n){
      accR[m][n] = (f32x4){0.f,0.f,0.f,0.f};
      accI[m][n] = (f32x4){0.f,0.f,0.f,0.f};
    }

  #pragma unroll
  for (int kp = 0; kp < 8; ++kp){
    short8b av[4], bR[2], bI[2];
    #pragma unroll
    for (int n = 0; n < 2; ++n){
      int col = w8*32 + n*16 + L;
      int off = col*256 + kp*32 + chk*8;
      bR[n] = *(const short8b*)&BtR[off];
      bI[n] = *(const short8b*)&BtI[off];
    }
    #pragma unroll
    for (int m = 0; m < 4; ++m){
      int row = m*16 + L;
      av[m] = *(const short8b*)&H3[row*256 + (((kp*4 + chk) ^ (L & 7)) << 3)];
    }
    #pragma unroll
    for (int m = 0; m < 4; ++m)
      #pragma unroll
      for (int n = 0; n < 2; ++n){
        accR[m][n] = __builtin_amdgcn_mfma_f32_16x16x32_bf16(av[m], bR[n], accR[m][n], 0,0,0);
        accI[m][n] = __builtin_amdgcn_mfma_f32_16x16x32_bf16(av[m], bI[n], accI[m][n], 0,0,0);
      }
  }

  // ---------- epilogue2: complex combine + bias, write packed planes directly ----------
  // out_re[j] = accR[top] - accI[bot];  out_im[j] = accI[top] + accR[bot]
  #pragma unroll
  for (int n = 0; n < 2; ++n){
    int col = w8*32 + n*16 + cl;
    float2 bg = b2g[col];
    #pragma unroll
    for (int m2 = 0; m2 < 2; ++m2){
      #pragma unroll
      for (int q = 0; q < 4; ++q){
        int j = m2*16 + cq*4 + q;
        float vr = accR[m2][n][q] - accI[m2+2][n][q] + bg.x;
        float vi = accI[m2][n][q] + accR[m2+2][n][q] + bg.y;
        OutP[(long)(cr0 + j)*256 + col] = packf2(vr, vi);
      }
    }
  }
}

// ---------------- m-axis IFFT: 16x16 four-step, in-place, 1024 thr x 64 v ----------------
__global__ __launch_bounds__(1024)
void fft_m(uint_t* __restrict__ P, const float2* __restrict__ ph){
  __shared__ uint_t Z[16384];          // [16 d][16 b][64 v] = 64KB
  const int tid = threadIdx.x;
  const int v  = tid & 63;
  const int bm = tid >> 6;             // 0..15
  const int bB = blockIdx.x >> 2;      // batch 0..511
  const int vg = (blockIdx.x & 3) << 6;
  const long base = (long)bB*65536 + vg + v;

  float xr[16], xi[16];
  #pragma unroll
  for (int a = 0; a < 16; ++a){
    uint_t u = P[base + (long)(a*16 + bm)*256];
    xr[a] = bf_lo(u); xi[a] = bf_hi(u);
  }
  fft16_inv(xr, xi);
  float2 ws = ph[bm];
  float wr = 1.f/256.f, wi = 0.f;      // folds 1/256
  #pragma unroll
  for (int d = 0; d < 16; ++d){
    float yr = xr[BR16T[d]], yi = xi[BR16T[d]];
    Z[d*1024 + bm*64 + v] = packf2(yr*wr - yi*wi, yr*wi + yi*wr);
    float nw = wr*ws.x - wi*ws.y; wi = wr*ws.y + wi*ws.x; wr = nw;
  }
  __syncthreads();
  const int d2 = tid >> 6;
  float br[16], bi[16];
  #pragma unroll
  for (int bb = 0; bb < 16; ++bb){
    uint_t u = Z[d2*1024 + bb*64 + v];
    br[bb] = bf_lo(u); bi[bb] = bf_hi(u);
  }
  fft16_inv(br, bi);
  #pragma unroll
  for (int p = 0; p < 16; ++p)
    P[base + (long)(BR16T[p]*16 + d2)*256] = packf2(br[p], bi[p]);
}

// ---------------- b-axis IFFT: 32x16 four-step, in-place, REAL fp32 out, 1024 thr x 64 v ----------------
// Transpose runs in two d-halves through a 64KB Z buffer (all input read to regs first).
__global__ __launch_bounds__(1024)
void fft_b(uint_t* __restrict__ P, const float2* __restrict__ t512){
  __shared__ uint_t Z[16384];          // [16 d][16 b][64 v] per half = 64KB
  const int tid = threadIdx.x;
  const int v  = tid & 63;
  const int bq = tid >> 6;             // 0..15
  const int m  = blockIdx.x >> 2;      // 0..255
  const int vg = (blockIdx.x & 3) << 6;
  const long base = (long)m*256 + vg + v;

  float xr[32], xi[32];
  #pragma unroll
  for (int a = 0; a < 32; ++a){
    uint_t u = P[base + (long)(a*16 + bq)*65536];
    xr[a] = bf_lo(u); xi[a] = bf_hi(u);
  }
  fft32_inv(xr, xi);
  float2 ws = t512[bq];
  float wr = 1.f/512.f, wi = 0.f;      // folds 1/512
  float* out = (float*)P;
  const int d2 = tid >> 6;

  // half 1: d in [0,16)
  #pragma unroll
  for (int d = 0; d < 16; ++d){
    float yr = xr[BR32T[d]], yi = xi[BR32T[d]];
    Z[d*1024 + bq*64 + v] = packf2(yr*wr - yi*wi, yr*wi + yi*wr);
    float nw = wr*ws.x - wi*ws.y; wi = wr*ws.y + wi*ws.x; wr = nw;
  }
  __syncthreads();
  {
    float br[16], bi[16];
    #pragma unroll
    for (int bb = 0; bb < 16; ++bb){
      uint_t u = Z[d2*1024 + bb*64 + v];
      br[bb] = bf_lo(u); bi[bb] = bf_hi(u);
    }
    fft16_inv(br, bi);
    #pragma unroll
    for (int p = 0; p < 16; ++p)
      out[base + (long)(BR16T[p]*32 + d2)*65536] = br[p];
  }
  __syncthreads();
  // half 2: d in [16,32)
  #pragma unroll
  for (int d = 16; d < 32; ++d){
    float yr = xr[BR32T[d]], yi = xi[BR32T[d]];
    Z[(d-16)*1024 + bq*64 + v] = packf2(yr*wr - yi*wi, yr*wi + yi*wr);
    float nw = wr*ws.x - wi*ws.y; wi = wr*ws.y + wi*ws.x; wr = nw;
  }
  __syncthreads();
  {
    float br[16], bi[16];
    #pragma unroll
    for (int bb = 0; bb < 16; ++bb){
      uint_t u = Z[d2*1024 + bb*64 + v];
      br[bb] = bf_lo(u); bi[bb] = bf_hi(u);
    }
    fft16_inv(br, bi);
    #pragma unroll
    for (int p = 0; p < 16; ++p)
      out[base + (long)(BR16T[p]*32 + (d2 + 16))*65536] = br[p];
  }
}

// ---------------- launch ----------------
extern "C" void kernel_launch(void* const* d_in, const int* in_sizes, int n_in,
                              void* d_out, int out_size, void* d_ws, size_t ws_size,
                              hipStream_t stream) {
  (void)in_sizes; (void)n_in; (void)out_size; (void)ws_size;
  const float* x      = (const float*)d_in[0];
  const float* w0     = (const float*)d_in[1];
  const float* w1     = (const float*)d_in[2];
  const float* lin1_w = (const float*)d_in[3];
  const float* lin1_b = (const float*)d_in[4];
  const float* lin2_w = (const float*)d_in[5];
  const float* lin2_b = (const float*)d_in[6];

  // ws smalls only (~3 MB)
  char* sm = (char*)d_ws;
  float2*   Yw     = (float2*)sm;   sm += 1048576;
  float*    Xr     = (float*)sm;    sm += 524288;
  float*    Xi     = (float*)sm;    sm += 524288;
  float2*   t256f  = (float2*)sm;   sm += 2048;
  float2*   t256i  = (float2*)sm;   sm += 2048;
  float2*   t512f  = (float2*)sm;   sm += 4096;
  float2*   t512i  = (float2*)sm;   sm += 4096;
  ushort_t* Wct    = (ushort_t*)sm; sm += 131072;
  ushort_t* BtR    = (ushort_t*)sm; sm += 131072;
  ushort_t* BtI    = (ushort_t*)sm; sm += 131072;
  float2*   b2g    = (float2*)sm;   sm += 2048;

  uint_t* planes = (uint_t*)d_out;    // packed bf16 complex planes, 134 MB

  fill_tables<<<1, 512, 0, stream>>>(t256f, t256i, t512f, t512i);
  dft_m<<<512, 256, 0, stream>>>(x, Yw, t256f);
  dft_b<<<512, 256, 0, stream>>>(Yw, Xr, Xi, t512f);
  prep_w<<<256, 256, 0, stream>>>(w1, lin1_w, Wct);
  prep_g<<<256, 256, 0, stream>>>(lin2_w, t256i, BtR, BtI);
  prep_b2g<<<1, 256, 0, stream>>>(lin2_b, t256i, b2g);
  fused_mid<<<4096, 512, 0, stream>>>(Xr, Xi, w0, Wct, BtR, BtI, lin1_b, b2g,
                                      t256i, planes);
  fft_m<<<2048, 1024, 0, stream>>>(planes, t256i);
  fft_b<<<1024, 1024, 0, stream>>>(planes, t512i);
}

// Round 12
// 336.431 us; speedup vs baseline: 1.2504x; 1.2504x over previous
//
#include <hip/hip_runtime.h>
#include <hip/hip_bf16.h>

// FNOBlock on MI355X — round 8: round-6 base + A-build algebraic cut + uint2 fft_m.
//   d_out (134 MB) holds packed bf16 complex planes (uint32) between IFFT stages,
//   overwritten in-place by the final real fp32 output.

typedef unsigned short ushort_t;
typedef unsigned int   uint_t;
typedef __attribute__((ext_vector_type(8))) short short8b;   // 8 x bf16
typedef __attribute__((ext_vector_type(4))) float f32x4;

__device__ __forceinline__ uint_t packf2(float lo, float hi){
  union { __hip_bfloat162 h; uint_t u; } v;
  v.h = __float22bfloat162_rn(make_float2(lo, hi));
  return v.u;
}
__device__ __forceinline__ ushort_t f2bf(float f){
  union { __hip_bfloat16 h; ushort_t u; } v;
  v.h = __float2bfloat16(f);
  return v.u;
}
__device__ __forceinline__ float bf_lo(uint_t u){
  union { uint_t u; float f; } v; v.u = u << 16; return v.f;
}
__device__ __forceinline__ float bf_hi(uint_t u){
  union { uint_t u; float f; } v; v.u = u & 0xFFFF0000u; return v.f;
}
__device__ __forceinline__ void gld16(const void* g, void* l){
  __builtin_amdgcn_global_load_lds(
      (const __attribute__((address_space(1))) void*)g,
      (__attribute__((address_space(3))) void*)l, 16, 0, 0);
}

// ---------------- register FFTs (inverse sign, DIF, out[p] = X[brev(p)]) ----------------
constexpr int BR16T[16] = {0,8,4,12,2,10,6,14,1,9,5,13,3,11,7,15};
constexpr int BR32T[32] = {0,16,8,24,4,20,12,28,2,18,10,26,6,22,14,30,
                           1,17,9,25,5,21,13,29,3,19,11,27,7,23,15,31};

__device__ __forceinline__ void bfly(float& ar, float& ai, float& br, float& bi,
                                     float wr, float wi){
  float sr = ar - br, si = ai - bi;
  ar += br; ai += bi;
  br = sr*wr - si*wi;
  bi = sr*wi + si*wr;
}

__device__ __forceinline__ void fft16_inv(float* xr, float* xi){
  const float C1 = 0.92387953251128674f, S1 = 0.38268343236508978f,
              C2 = 0.70710678118654752f;
  bfly(xr[0],xi[0],xr[8],xi[8],    1.f, 0.f);
  bfly(xr[1],xi[1],xr[9],xi[9],    C1,  S1);
  bfly(xr[2],xi[2],xr[10],xi[10],  C2,  C2);
  bfly(xr[3],xi[3],xr[11],xi[11],  S1,  C1);
  bfly(xr[4],xi[4],xr[12],xi[12],  0.f, 1.f);
  bfly(xr[5],xi[5],xr[13],xi[13], -S1,  C1);
  bfly(xr[6],xi[6],xr[14],xi[14], -C2,  C2);
  bfly(xr[7],xi[7],xr[15],xi[15], -C1,  S1);
  #pragma unroll
  for (int h = 0; h < 16; h += 8){
    bfly(xr[h+0],xi[h+0],xr[h+4],xi[h+4],  1.f, 0.f);
    bfly(xr[h+1],xi[h+1],xr[h+5],xi[h+5],  C2,  C2);
    bfly(xr[h+2],xi[h+2],xr[h+6],xi[h+6],  0.f, 1.f);
    bfly(xr[h+3],xi[h+3],xr[h+7],xi[h+7], -C2,  C2);
  }
  #pragma unroll
  for (int h = 0; h < 16; h += 4){
    bfly(xr[h+0],xi[h+0],xr[h+2],xi[h+2], 1.f, 0.f);
    bfly(xr[h+1],xi[h+1],xr[h+3],xi[h+3], 0.f, 1.f);
  }
  #pragma unroll
  for (int h = 0; h < 16; h += 2)
    bfly(xr[h],xi[h],xr[h+1],xi[h+1], 1.f, 0.f);
}

__device__ __forceinline__ void fft32_inv(float* xr, float* xi){
  constexpr float WR[16] = {
    1.f, 0.98078528040323044f, 0.92387953251128674f, 0.83146961230254524f,
    0.70710678118654752f, 0.55557023301960222f, 0.38268343236508978f, 0.19509032201612827f,
    0.f,-0.19509032201612827f,-0.38268343236508978f,-0.55557023301960222f,
   -0.70710678118654752f,-0.83146961230254524f,-0.92387953251128674f,-0.98078528040323044f};
  constexpr float WI[16] = {
    0.f, 0.19509032201612827f, 0.38268343236508978f, 0.55557023301960222f,
    0.70710678118654752f, 0.83146961230254524f, 0.92387953251128674f, 0.98078528040323044f,
    1.f, 0.98078528040323044f, 0.92387953251128674f, 0.83146961230254524f,
    0.70710678118654752f, 0.55557023301960222f, 0.38268343236508978f, 0.19509032201612827f};
  #pragma unroll
  for (int j = 0; j < 16; ++j)
    bfly(xr[j],xi[j],xr[j+16],xi[j+16], WR[j], WI[j]);
  fft16_inv(xr, xi);
  fft16_inv(xr+16, xi+16);
}

// ---------------- tables ----------------
__global__ void fill_tables(float2* t256f, float2* t256i, float2* t512f, float2* t512i){
  int i = threadIdx.x;              // 512 threads
  const double PI2 = 6.283185307179586476925286766559;
  if (i < 256){
    double a = PI2 * (double)i / 256.0;
    float c = (float)cos(a), s = (float)sin(a);
    t256f[i] = make_float2(c, -s);
    t256i[i] = make_float2(c,  s);
  }
  {
    double a = PI2 * (double)i / 512.0;
    float c = (float)cos(a), s = (float)sin(a);
    t512f[i] = make_float2(c, -s);
    t512i[i] = make_float2(c,  s);
  }
}

// ---------------- forward fft2 of x (naive DFTs, tiny) ----------------
__global__ void dft_m(const float* __restrict__ x, float2* __restrict__ Yw,
                      const float2* __restrict__ twf){
  __shared__ float xs[256];
  __shared__ float2 tws[256];
  int b = blockIdx.x, k = threadIdx.x;
  xs[k]  = x[b*256 + k];
  tws[k] = twf[k];
  __syncthreads();
  float yr = 0.f, yi = 0.f;
  for (int m = 0; m < 256; ++m){
    float2 w = tws[(m*k) & 255];
    float xv = xs[m];
    yr += xv*w.x; yi += xv*w.y;
  }
  Yw[b*256 + k] = make_float2(yr, yi);
}

__global__ void dft_b(const float2* __restrict__ Yw, float* __restrict__ Xr,
                      float* __restrict__ Xi, const float2* __restrict__ twf){
  __shared__ float2 tws[512];
  int j = blockIdx.x, k = threadIdx.x;
  tws[k]       = twf[k];
  tws[k + 256] = twf[k + 256];
  __syncthreads();
  float xr = 0.f, xi = 0.f;
  for (int b = 0; b < 512; ++b){
    float2 y = Yw[b*256 + k];
    float2 w = tws[(b*j) & 511];
    xr += y.x*w.x - y.y*w.y;
    xi += y.x*w.y + y.y*w.x;
  }
  Xr[j*256 + k] = xr;
  Xi[j*256 + k] = xi;
}

// ---------------- weight prep ----------------
// Wct[u][t] = sum_v lin1_w[u][v]*w1[t][v]  (bf16)
__global__ void prep_w(const float* __restrict__ w1, const float* __restrict__ lin1_w,
                       ushort_t* __restrict__ Wct){
  __shared__ float l1[256];
  int u = blockIdx.x, t = threadIdx.x;
  l1[t] = lin1_w[u*256 + t];
  __syncthreads();
  float s = 0.f;
  for (int v = 0; v < 256; ++v)
    s += l1[v] * w1[t*256 + v];
  Wct[u*256 + t] = f2bf(s);
}

// M[k][v] = sum_u lin2_w[u][k] * e^{2pi i uv/256}/256 ; Bt*[v][k] = M[k][v]
__global__ void prep_g(const float* __restrict__ lin2_w, const float2* __restrict__ ph,
                       ushort_t* __restrict__ BtR, ushort_t* __restrict__ BtI){
  int v = blockIdx.x, k = threadIdx.x;
  float cre = 0.f, cim = 0.f;
  for (int u = 0; u < 256; ++u){
    float w = lin2_w[u*256 + k];
    float2 t = ph[(u*v) & 255];
    cre += w*t.x; cim += w*t.y;
  }
  BtR[v*256 + k] = f2bf(cre * (1.f/256.f));
  BtI[v*256 + k] = f2bf(cim * (1.f/256.f));
}

// b2g[v] = sum_u b2[u] * e^{2pi i uv/256}/256
__global__ void prep_b2g(const float* __restrict__ b2, const float2* __restrict__ ph,
                         float2* __restrict__ b2g){
  int v = threadIdx.x;
  float cre = 0.f, cim = 0.f;
  for (int u = 0; u < 256; ++u){
    float w = b2[u];
    float2 t = ph[(u*v) & 255];
    cre += w*t.x; cim += w*t.y;
  }
  b2g[v] = make_float2(cre * (1.f/256.f), cim * (1.f/256.f));
}

// ---------------- fused: h0 build + GEMM1 + GEMM2(+v-IFFT) -> packed planes ----------------
// 512 threads (8 waves), 32 complex rows per block (stacked rows: [re 0..31][im 32..63]).
// Wave w owns output cols [32w, 32w+32). K-step 32, A/B double-buffered via gld16.
// LDS (64 KB): [Bt dbuf 0..32K][At dbuf 32K..40K / H3 32K..64K].
__global__ __launch_bounds__(512, 4)
void fused_mid(const float* __restrict__ Xr, const float* __restrict__ Xi,
               const float* __restrict__ w0,
               const ushort_t* __restrict__ Wct,
               const ushort_t* __restrict__ BtR, const ushort_t* __restrict__ BtI,
               const float* __restrict__ b1, const float2* __restrict__ b2g,
               const float2* __restrict__ ph,      // e^{+2pi i k/256}
               uint_t* __restrict__ OutP)
{
  __shared__ __align__(16) char lds[65536];
  ushort_t* H3 = (ushort_t*)(lds + 32768);   // [64][256] bf16 (after GEMM1)

  const int tid  = threadIdx.x;
  const int lane = tid & 63;
  const int w8   = tid >> 6;          // wave 0..7
  const int L    = lane & 15;
  const int chk  = lane >> 4;         // 0..3 (k-chunk / C-row-quad)
  const int cq   = chk, cl = L;
  const int cr0  = blockIdx.x * 32;

  // ---- A-build constants: relu(x*w) = w * (w>0 ? max(x,0) : min(x,0)), phase folded ----
  const int arow = tid >> 3;           // stacked row 0..63
  const int ak0  = (tid & 7) * 4;      // k within 32-tile
  const int ajj  = arow & 31;
  const bool aim = arow >= 32;
  const float axr = Xr[cr0 + ajj];
  const float axi = Xi[cr0 + ajj];
  const int am = (cr0 + ajj) & 255;    // w0 row (mode)
  const float2 apj = ph[am];
  const float axp = fmaxf(axr, 0.f), axm = fminf(axr, 0.f);
  const float ayp = fmaxf(axi, 0.f), aym = fminf(axi, 0.f);
  const float aCp = aim ? (apj.y*axp + apj.x*ayp) : (apj.x*axp - apj.y*ayp);
  const float aCm = aim ? (apj.y*axm + apj.x*aym) : (apj.x*axm - apj.y*aym);
  const int aslot = (ak0 >> 3) ^ ((arow >> 1) & 3);
  const int aoff  = arow*64 + aslot*16 + (ak0 & 7)*2;   // byte offset in At buffer

  // ---- fragment read indices (ushort units) ----
  const int fsl  = chk ^ ((L >> 1) & 3);
  const int avix = L*32 + fsl*8;             // + m*512
  const int bvix = w8*1024 + avix;           // + n*512

  // ---- B staging constants (2 gld16/thread) ----
  const int bc = (tid & 3) ^ ((tid >> 3) & 3);   // source k-chunk for this slot

  #define STAGE_B(W, kt, bsel) do {                                        \
    char* _d = lds + (bsel)*16384 + tid*16;                                \
    _Pragma("unroll")                                                      \
    for (int _i = 0; _i < 2; ++_i){                                        \
      int _row = _i*128 + (tid >> 2);                                      \
      gld16((W) + _row*256 + (kt)*32 + bc*8, _d + _i*8192);                \
    }                                                                      \
  } while(0)

  #define STAGE_A(kt, bsel) do {                                           \
    const float4 _w4 = *(const float4*)&w0[(size_t)am*256 + (kt)*32 + ak0];\
    float _wv[4] = {_w4.x, _w4.y, _w4.z, _w4.w};                           \
    float _va[4];                                                          \
    _Pragma("unroll")                                                      \
    for (int _e = 0; _e < 4; ++_e)                                         \
      _va[_e] = _wv[_e] * (_wv[_e] > 0.f ? aCp : aCm);                     \
    *(uint2*)(lds + 32768 + (bsel)*4096 + aoff) =                          \
        make_uint2(packf2(_va[0], _va[1]), packf2(_va[2], _va[3]));        \
  } while(0)

  // ---------- GEMM1: acc = A(64x256) @ Wct^T ----------
  f32x4 acc[4][2];
  #pragma unroll
  for (int m = 0; m < 4; ++m)
    #pragma unroll
    for (int n = 0; n < 2; ++n)
      acc[m][n] = (f32x4){0.f,0.f,0.f,0.f};

  int buf = 0;
  STAGE_B(Wct, 0, 0);
  STAGE_A(0, 0);
  __syncthreads();
  for (int kt = 0; kt < 8; ++kt){
    if (kt < 7){ STAGE_B(Wct, kt+1, buf^1); STAGE_A(kt+1, buf^1); }
    const ushort_t* Ab = (const ushort_t*)(lds + 32768 + buf*4096);
    const ushort_t* Bb = (const ushort_t*)(lds + buf*16384);
    short8b av[4], bv[2];
    #pragma unroll
    for (int m = 0; m < 4; ++m) av[m] = *(const short8b*)&Ab[avix + m*512];
    #pragma unroll
    for (int n = 0; n < 2; ++n) bv[n] = *(const short8b*)&Bb[bvix + n*512];
    #pragma unroll
    for (int m = 0; m < 4; ++m)
      #pragma unroll
      for (int n = 0; n < 2; ++n)
        acc[m][n] = __builtin_amdgcn_mfma_f32_16x16x32_bf16(av[m], bv[n], acc[m][n], 0,0,0);
    __syncthreads();
    buf ^= 1;
  }

  // ---------- epilogue1: h3 = relu(acc + b1(re rows)) -> H3 bf16 (swizzled) ----------
  STAGE_B(BtR, 0, 0);      // prefetch GEMM2 step 0 (buf 0 is free after kt=7)
  #pragma unroll
  for (int m = 0; m < 4; ++m){
    #pragma unroll
    for (int n = 0; n < 2; ++n){
      int col = w8*32 + n*16 + cl;
      float badd = (m < 2) ? b1[col] : 0.f;
      #pragma unroll
      for (int q = 0; q < 4; ++q){
        int row = m*16 + cq*4 + q;
        float v = fmaxf(acc[m][n][q] + badd, 0.f);
        int s = (col >> 3) ^ (row & 7);
        H3[row*256 + s*8 + (col & 7)] = f2bf(v);
      }
    }
  }
  __syncthreads();

  // ---------- GEMM2: accR = H3 @ BtR^T, accI = H3 @ BtI^T (alternating dbuf steps) ----------
  f32x4 accR[4][2], accI[4][2];
  #pragma unroll
  for (int m = 0; m < 4; ++m)
    #pragma unroll
    for (int n = 0; n < 2; ++n){
      accR[m][n] = (f32x4){0.f,0.f,0.f,0.f};
      accI[m][n] = (f32x4){0.f,0.f,0.f,0.f};
    }

  buf = 0;
  for (int kp = 0; kp < 8; ++kp){
    short8b av[4], bv[2];
    #pragma unroll
    for (int m = 0; m < 4; ++m){
      int r = m*16 + L;
      int sl = (kp*4 + chk) ^ (r & 7);
      av[m] = *(const short8b*)&H3[r*256 + sl*8];
    }
    // even step: compute Re from buf, stage Im(kp) into buf^1
    STAGE_B(BtI, kp, buf^1);
    {
      const ushort_t* Bb = (const ushort_t*)(lds + buf*16384);
      #pragma unroll
      for (int n = 0; n < 2; ++n) bv[n] = *(const short8b*)&Bb[bvix + n*512];
      #pragma unroll
      for (int m = 0; m < 4; ++m)
        #pragma unroll
        for (int n = 0; n < 2; ++n)
          accR[m][n] = __builtin_amdgcn_mfma_f32_16x16x32_bf16(av[m], bv[n], accR[m][n], 0,0,0);
    }
    __syncthreads();
    buf ^= 1;
    // odd step: compute Im from buf, stage Re(kp+1) into buf^1
    if (kp < 7) STAGE_B(BtR, kp+1, buf^1);
    {
      const ushort_t* Bb = (const ushort_t*)(lds + buf*16384);
      #pragma unroll
      for (int n = 0; n < 2; ++n) bv[n] = *(const short8b*)&Bb[bvix + n*512];
      #pragma unroll
      for (int m = 0; m < 4; ++m)
        #pragma unroll
        for (int n = 0; n < 2; ++n)
          accI[m][n] = __builtin_amdgcn_mfma_f32_16x16x32_bf16(av[m], bv[n], accI[m][n], 0,0,0);
    }
    __syncthreads();
    buf ^= 1;
  }

  // ---------- epilogue2: complex combine + bias, write packed planes directly ----------
  // out_re[j] = accR[top] - accI[bot];  out_im[j] = accI[top] + accR[bot]
  #pragma unroll
  for (int n = 0; n < 2; ++n){
    int col = w8*32 + n*16 + cl;
    float2 bg = b2g[col];
    #pragma unroll
    for (int m2 = 0; m2 < 2; ++m2){
      #pragma unroll
      for (int q = 0; q < 4; ++q){
        int j = m2*16 + cq*4 + q;
        float vr = accR[m2][n][q]   - accI[m2+2][n][q] + bg.x;
        float vi = accI[m2][n][q]   + accR[m2+2][n][q] + bg.y;
        OutP[(long)(cr0 + j)*256 + col] = packf2(vr, vi);
      }
    }
  }
  #undef STAGE_B
  #undef STAGE_A
}

// ---------------- m-axis IFFT: 16x16 four-step, in-place, 256 thr, uint2 (v-pairs) ----------------
__global__ __launch_bounds__(256)
void fft_m(uint_t* __restrict__ P, const float2* __restrict__ ph){
  __shared__ __align__(16) uint_t Z[16*546];   // [d (stride 546)][bm (stride 34)][32 v] ~34.9KB
  const int tid = threadIdx.x;
  const int p   = tid & 15;            // v-pair index: v = vg + 2p, 2p+1
  const int bm  = tid >> 4;            // 0..15
  const int bB  = blockIdx.x >> 3;     // batch 0..511
  const int vg  = (blockIdx.x & 7) << 5;
  const long base = (long)bB*65536 + vg + 2*p;

  float xr0[16], xi0[16], xr1[16], xi1[16];
  #pragma unroll
  for (int a = 0; a < 16; ++a){
    uint2 u = *(const uint2*)&P[base + (long)(a*16 + bm)*256];
    xr0[a] = bf_lo(u.x); xi0[a] = bf_hi(u.x);
    xr1[a] = bf_lo(u.y); xi1[a] = bf_hi(u.y);
  }
  fft16_inv(xr0, xi0);
  fft16_inv(xr1, xi1);
  float2 ws = ph[bm];
  float wr = 1.f/256.f, wi = 0.f;      // folds 1/256
  #pragma unroll
  for (int d = 0; d < 16; ++d){
    int s = BR16T[d];
    float ar0 = xr0[s], ai0 = xi0[s], ar1 = xr1[s], ai1 = xi1[s];
    *(uint2*)&Z[d*546 + bm*34 + 2*p] = make_uint2(
        packf2(ar0*wr - ai0*wi, ar0*wi + ai0*wr),
        packf2(ar1*wr - ai1*wi, ar1*wi + ai1*wr));
    float nw = wr*ws.x - wi*ws.y; wi = wr*ws.y + wi*ws.x; wr = nw;
  }
  __syncthreads();
  const int d2 = tid >> 4;
  float br0[16], bi0[16], br1[16], bi1[16];
  #pragma unroll
  for (int bb = 0; bb < 16; ++bb){
    uint2 u = *(const uint2*)&Z[d2*546 + bb*34 + 2*p];
    br0[bb] = bf_lo(u.x); bi0[bb] = bf_hi(u.x);
    br1[bb] = bf_lo(u.y); bi1[bb] = bf_hi(u.y);
  }
  fft16_inv(br0, bi0);
  fft16_inv(br1, bi1);
  #pragma unroll
  for (int q = 0; q < 16; ++q){
    int k = BR16T[q]*16 + d2;
    *(uint2*)&P[base + (long)k*256] =
        make_uint2(packf2(br0[q], bi0[q]), packf2(br1[q], bi1[q]));
  }
}

// ---------------- b-axis IFFT: 32x16 four-step, in-place, REAL fp32 out, 512 thr x 32 v ----------------
__global__ __launch_bounds__(512)
void fft_b(uint_t* __restrict__ P, const float2* __restrict__ t512){
  __shared__ uint_t Z[16384];          // [32 d][16 b][32 v] = 64KB, unpadded
  const int tid = threadIdx.x;
  const int v  = tid & 31;
  const int bq = tid >> 5;             // 0..15
  const int m  = blockIdx.x >> 3;      // 0..255
  const int vg = (blockIdx.x & 7) << 5;
  const long base = (long)m*256 + vg + v;

  float xr[32], xi[32];
  #pragma unroll
  for (int a = 0; a < 32; ++a){
    uint_t u = P[base + (long)(a*16 + bq)*65536];
    xr[a] = bf_lo(u); xi[a] = bf_hi(u);
  }
  fft32_inv(xr, xi);
  float2 ws = t512[bq];
  float wr = 1.f/512.f, wi = 0.f;      // folds 1/512
  #pragma unroll
  for (int d = 0; d < 32; ++d){
    float yr = xr[BR32T[d]], yi = xi[BR32T[d]];
    Z[d*512 + bq*32 + v] = packf2(yr*wr - yi*wi, yr*wi + yi*wr);
    float nw = wr*ws.x - wi*ws.y; wi = wr*ws.y + wi*ws.x; wr = nw;
  }
  __syncthreads();
  float* out = (float*)P;
  #pragma unroll
  for (int h = 0; h < 2; ++h){
    const int d = (tid >> 5) + 16*h;
    float br[16], bi[16];
    #pragma unroll
    for (int bb = 0; bb < 16; ++bb){
      uint_t u = Z[d*512 + bb*32 + v];
      br[bb] = bf_lo(u); bi[bb] = bf_hi(u);
    }
    fft16_inv(br, bi);
    #pragma unroll
    for (int p = 0; p < 16; ++p)
      out[base + (long)(BR16T[p]*32 + d)*65536] = br[p];
  }
}

// ---------------- launch ----------------
extern "C" void kernel_launch(void* const* d_in, const int* in_sizes, int n_in,
                              void* d_out, int out_size, void* d_ws, size_t ws_size,
                              hipStream_t stream) {
  (void)in_sizes; (void)n_in; (void)out_size; (void)ws_size;
  const float* x      = (const float*)d_in[0];
  const float* w0     = (const float*)d_in[1];
  const float* w1     = (const float*)d_in[2];
  const float* lin1_w = (const float*)d_in[3];
  const float* lin1_b = (const float*)d_in[4];
  const float* lin2_w = (const float*)d_in[5];
  const float* lin2_b = (const float*)d_in[6];

  // ws smalls only (~3 MB)
  char* sm = (char*)d_ws;
  float2*   Yw     = (float2*)sm;   sm += 1048576;
  float*    Xr     = (float*)sm;    sm += 524288;
  float*    Xi     = (float*)sm;    sm += 524288;
  float2*   t256f  = (float2*)sm;   sm += 2048;
  float2*   t256i  = (float2*)sm;   sm += 2048;
  float2*   t512f  = (float2*)sm;   sm += 4096;
  float2*   t512i  = (float2*)sm;   sm += 4096;
  ushort_t* Wct    = (ushort_t*)sm; sm += 131072;
  ushort_t* BtR    = (ushort_t*)sm; sm += 131072;
  ushort_t* BtI    = (ushort_t*)sm; sm += 131072;
  float2*   b2g    = (float2*)sm;   sm += 2048;

  uint_t* planes = (uint_t*)d_out;    // packed bf16 complex planes, 134 MB

  fill_tables<<<1, 512, 0, stream>>>(t256f, t256i, t512f, t512i);
  dft_m<<<512, 256, 0, stream>>>(x, Yw, t256f);
  dft_b<<<512, 256, 0, stream>>>(Yw, Xr, Xi, t512f);
  prep_w<<<256, 256, 0, stream>>>(w1, lin1_w, Wct);
  prep_g<<<256, 256, 0, stream>>>(lin2_w, t256i, BtR, BtI);
  prep_b2g<<<1, 256, 0, stream>>>(lin2_b, t256i, b2g);
  fused_mid<<<4096, 512, 0, stream>>>(Xr, Xi, w0, Wct, BtR, BtI, lin1_b, b2g,
                                      t256i, planes);
  fft_m<<<4096, 256, 0, stream>>>(planes, t256i);
  fft_b<<<2048, 512, 0, stream>>>(planes, t512i);
}

// Round 13
// 290.566 us; speedup vs baseline: 1.4478x; 1.1578x over previous
//
#include <hip/hip_runtime.h>
#include <hip/hip_bf16.h>

// FNOBlock on MI355X — round 9: composite of best-measured components.
//   fused_mid: round-5 version verbatim (149.8 µs measured).
//   fft_m: round-8 uint2 version verbatim; fft_b: round-8 version verbatim (~143 µs combined).
//   d_out (134 MB) holds packed bf16 complex planes (uint32) between IFFT stages,
//   overwritten in-place by the final real fp32 output.

typedef unsigned short ushort_t;
typedef unsigned int   uint_t;
typedef __attribute__((ext_vector_type(8))) short short8b;   // 8 x bf16
typedef __attribute__((ext_vector_type(4))) float f32x4;

__device__ __forceinline__ uint_t packf2(float lo, float hi){
  union { __hip_bfloat162 h; uint_t u; } v;
  v.h = __float22bfloat162_rn(make_float2(lo, hi));
  return v.u;
}
__device__ __forceinline__ ushort_t f2bf(float f){
  union { __hip_bfloat16 h; ushort_t u; } v;
  v.h = __float2bfloat16(f);
  return v.u;
}
__device__ __forceinline__ float bf_lo(uint_t u){
  union { uint_t u; float f; } v; v.u = u << 16; return v.f;
}
__device__ __forceinline__ float bf_hi(uint_t u){
  union { uint_t u; float f; } v; v.u = u & 0xFFFF0000u; return v.f;
}
__device__ __forceinline__ void gld16(const void* g, void* l){
  __builtin_amdgcn_global_load_lds(
      (const __attribute__((address_space(1))) void*)g,
      (__attribute__((address_space(3))) void*)l, 16, 0, 0);
}

// ---------------- register FFTs (inverse sign, DIF, out[p] = X[brev(p)]) ----------------
constexpr int BR16T[16] = {0,8,4,12,2,10,6,14,1,9,5,13,3,11,7,15};
constexpr int BR32T[32] = {0,16,8,24,4,20,12,28,2,18,10,26,6,22,14,30,
                           1,17,9,25,5,21,13,29,3,19,11,27,7,23,15,31};

__device__ __forceinline__ void bfly(float& ar, float& ai, float& br, float& bi,
                                     float wr, float wi){
  float sr = ar - br, si = ai - bi;
  ar += br; ai += bi;
  br = sr*wr - si*wi;
  bi = sr*wi + si*wr;
}

__device__ __forceinline__ void fft16_inv(float* xr, float* xi){
  const float C1 = 0.92387953251128674f, S1 = 0.38268343236508978f,
              C2 = 0.70710678118654752f;
  bfly(xr[0],xi[0],xr[8],xi[8],    1.f, 0.f);
  bfly(xr[1],xi[1],xr[9],xi[9],    C1,  S1);
  bfly(xr[2],xi[2],xr[10],xi[10],  C2,  C2);
  bfly(xr[3],xi[3],xr[11],xi[11],  S1,  C1);
  bfly(xr[4],xi[4],xr[12],xi[12],  0.f, 1.f);
  bfly(xr[5],xi[5],xr[13],xi[13], -S1,  C1);
  bfly(xr[6],xi[6],xr[14],xi[14], -C2,  C2);
  bfly(xr[7],xi[7],xr[15],xi[15], -C1,  S1);
  #pragma unroll
  for (int h = 0; h < 16; h += 8){
    bfly(xr[h+0],xi[h+0],xr[h+4],xi[h+4],  1.f, 0.f);
    bfly(xr[h+1],xi[h+1],xr[h+5],xi[h+5],  C2,  C2);
    bfly(xr[h+2],xi[h+2],xr[h+6],xi[h+6],  0.f, 1.f);
    bfly(xr[h+3],xi[h+3],xr[h+7],xi[h+7], -C2,  C2);
  }
  #pragma unroll
  for (int h = 0; h < 16; h += 4){
    bfly(xr[h+0],xi[h+0],xr[h+2],xi[h+2], 1.f, 0.f);
    bfly(xr[h+1],xi[h+1],xr[h+3],xi[h+3], 0.f, 1.f);
  }
  #pragma unroll
  for (int h = 0; h < 16; h += 2)
    bfly(xr[h],xi[h],xr[h+1],xi[h+1], 1.f, 0.f);
}

__device__ __forceinline__ void fft32_inv(float* xr, float* xi){
  constexpr float WR[16] = {
    1.f, 0.98078528040323044f, 0.92387953251128674f, 0.83146961230254524f,
    0.70710678118654752f, 0.55557023301960222f, 0.38268343236508978f, 0.19509032201612827f,
    0.f,-0.19509032201612827f,-0.38268343236508978f,-0.55557023301960222f,
   -0.70710678118654752f,-0.83146961230254524f,-0.92387953251128674f,-0.98078528040323044f};
  constexpr float WI[16] = {
    0.f, 0.19509032201612827f, 0.38268343236508978f, 0.55557023301960222f,
    0.70710678118654752f, 0.83146961230254524f, 0.92387953251128674f, 0.98078528040323044f,
    1.f, 0.98078528040323044f, 0.92387953251128674f, 0.83146961230254524f,
    0.70710678118654752f, 0.55557023301960222f, 0.38268343236508978f, 0.19509032201612827f};
  #pragma unroll
  for (int j = 0; j < 16; ++j)
    bfly(xr[j],xi[j],xr[j+16],xi[j+16], WR[j], WI[j]);
  fft16_inv(xr, xi);
  fft16_inv(xr+16, xi+16);
}

// ---------------- tables ----------------
__global__ void fill_tables(float2* t256f, float2* t256i, float2* t512f, float2* t512i){
  int i = threadIdx.x;              // 512 threads
  const double PI2 = 6.283185307179586476925286766559;
  if (i < 256){
    double a = PI2 * (double)i / 256.0;
    float c = (float)cos(a), s = (float)sin(a);
    t256f[i] = make_float2(c, -s);
    t256i[i] = make_float2(c,  s);
  }
  {
    double a = PI2 * (double)i / 512.0;
    float c = (float)cos(a), s = (float)sin(a);
    t512f[i] = make_float2(c, -s);
    t512i[i] = make_float2(c,  s);
  }
}

// ---------------- forward fft2 of x (naive DFTs, tiny) ----------------
__global__ void dft_m(const float* __restrict__ x, float2* __restrict__ Yw,
                      const float2* __restrict__ twf){
  __shared__ float xs[256];
  __shared__ float2 tws[256];
  int b = blockIdx.x, k = threadIdx.x;
  xs[k]  = x[b*256 + k];
  tws[k] = twf[k];
  __syncthreads();
  float yr = 0.f, yi = 0.f;
  for (int m = 0; m < 256; ++m){
    float2 w = tws[(m*k) & 255];
    float xv = xs[m];
    yr += xv*w.x; yi += xv*w.y;
  }
  Yw[b*256 + k] = make_float2(yr, yi);
}

__global__ void dft_b(const float2* __restrict__ Yw, float* __restrict__ Xr,
                      float* __restrict__ Xi, const float2* __restrict__ twf){
  __shared__ float2 tws[512];
  int j = blockIdx.x, k = threadIdx.x;
  tws[k]       = twf[k];
  tws[k + 256] = twf[k + 256];
  __syncthreads();
  float xr = 0.f, xi = 0.f;
  for (int b = 0; b < 512; ++b){
    float2 y = Yw[b*256 + k];
    float2 w = tws[(b*j) & 511];
    xr += y.x*w.x - y.y*w.y;
    xi += y.x*w.y + y.y*w.x;
  }
  Xr[j*256 + k] = xr;
  Xi[j*256 + k] = xi;
}

// ---------------- weight prep ----------------
__global__ void prep_w(const float* __restrict__ w1, const float* __restrict__ lin1_w,
                       const float* __restrict__ lin2_w,
                       ushort_t* __restrict__ Wct, ushort_t* __restrict__ W2b){
  __shared__ float l1[256];
  int u = blockIdx.x, t = threadIdx.x;
  l1[t] = lin1_w[u*256 + t];
  __syncthreads();
  float s = 0.f;
  for (int v = 0; v < 256; ++v)
    s += l1[v] * w1[t*256 + v];
  Wct[u*256 + t] = f2bf(s);
  W2b[u*256 + t] = f2bf(lin2_w[u*256 + t]);
}

// ---------------- fused: h0 build + GEMM1 + GEMM2 + v-IFFT -> packed planes ----------------
// 512 threads (8 waves), 32 complex rows per block (stacked rows: [re 0..31][im 32..63]).
// Wave w owns output cols [32w, 32w+32). K-step 32, A/B double-buffered.
// LDS (64 KB): [Bt dbuf 0..32K][At dbuf 32K..40K / H3 32K..64K]; Z (38 KB) overlays post-GEMM2.
#define ZJS 300   // Z j-stride (uints): mult of 4 (b128 align), %32=12 (bank spread)

__global__ __launch_bounds__(512, 4)
void fused_mid(const float* __restrict__ Xr, const float* __restrict__ Xi,
               const float* __restrict__ w0,
               const ushort_t* __restrict__ Wct, const ushort_t* __restrict__ W2b,
               const float* __restrict__ b1, const float* __restrict__ b2,
               const float2* __restrict__ ph,      // e^{+2pi i k/256}
               uint_t* __restrict__ OutP)
{
  __shared__ __align__(16) char lds[65536];
  ushort_t* H3 = (ushort_t*)(lds + 32768);   // [64][256] bf16 (after GEMM1)
  uint_t*   Z  = (uint_t*)lds;               // post-GEMM2 overlay

  const int tid  = threadIdx.x;
  const int lane = tid & 63;
  const int w8   = tid >> 6;          // wave 0..7
  const int L    = lane & 15;
  const int chk  = lane >> 4;         // 0..3 (k-chunk / C-row-quad)
  const int cq   = chk, cl = L;
  const int cr0  = blockIdx.x * 32;

  // ---- A-build constants (thread builds 4 bf16 of the A tile per kt) ----
  const int arow = tid >> 3;           // stacked row 0..63
  const int ak0  = (tid & 7) * 4;      // k within 32-tile
  const int ajj  = arow & 31;
  const bool aim = arow >= 32;
  const float axr = Xr[cr0 + ajj];
  const float axi = Xi[cr0 + ajj];
  const float2 apj = ph[(cr0 + ajj) & 255];
  const int am = (cr0 + ajj) & 255;    // w0 row (mode)
  const int aslot = (ak0 >> 3) ^ ((arow >> 1) & 3);
  const int aoff  = arow*64 + aslot*16 + (ak0 & 7)*2;   // byte offset in At buffer

  // ---- fragment read indices (ushort units) ----
  const int fsl  = chk ^ ((L >> 1) & 3);
  const int avix = L*32 + fsl*8;             // + m*512
  const int bvix = w8*1024 + avix;           // + n*512

  // ---- B staging constants (2 gld16/thread) ----
  const int bc = (tid & 3) ^ ((tid >> 3) & 3);   // source k-chunk for this slot

  #define STAGE_B(W, kt, bsel) do {                                        \
    char* _d = lds + (bsel)*16384 + tid*16;                                \
    _Pragma("unroll")                                                      \
    for (int _i = 0; _i < 2; ++_i){                                        \
      int _row = _i*128 + (tid >> 2);                                      \
      gld16((W) + _row*256 + (kt)*32 + bc*8, _d + _i*8192);                \
    }                                                                      \
  } while(0)

  #define STAGE_A(kt, bsel) do {                                           \
    const float4 _w4 = *(const float4*)&w0[(size_t)am*256 + (kt)*32 + ak0];\
    float _wv[4] = {_w4.x, _w4.y, _w4.z, _w4.w};                           \
    float _va[4];                                                          \
    _Pragma("unroll")                                                      \
    for (int _e = 0; _e < 4; ++_e){                                        \
      float _r = fmaxf(axr*_wv[_e], 0.f);                                  \
      float _m = fmaxf(axi*_wv[_e], 0.f);                                  \
      _va[_e] = aim ? (apj.y*_r + apj.x*_m) : (apj.x*_r - apj.y*_m);       \
    }                                                                      \
    *(uint2*)(lds + 32768 + (bsel)*4096 + aoff) =                          \
        make_uint2(packf2(_va[0], _va[1]), packf2(_va[2], _va[3]));        \
  } while(0)

  // ---------- GEMM1: acc = A(64x256) @ Wct^T ----------
  f32x4 acc[4][2];
  #pragma unroll
  for (int m = 0; m < 4; ++m)
    #pragma unroll
    for (int n = 0; n < 2; ++n)
      acc[m][n] = (f32x4){0.f,0.f,0.f,0.f};

  int buf = 0;
  STAGE_B(Wct, 0, 0);
  STAGE_A(0, 0);
  __syncthreads();
  for (int kt = 0; kt < 8; ++kt){
    if (kt < 7){ STAGE_B(Wct, kt+1, buf^1); STAGE_A(kt+1, buf^1); }
    const ushort_t* Ab = (const ushort_t*)(lds + 32768 + buf*4096);
    const ushort_t* Bb = (const ushort_t*)(lds + buf*16384);
    short8b av[4], bv[2];
    #pragma unroll
    for (int m = 0; m < 4; ++m) av[m] = *(const short8b*)&Ab[avix + m*512];
    #pragma unroll
    for (int n = 0; n < 2; ++n) bv[n] = *(const short8b*)&Bb[bvix + n*512];
    #pragma unroll
    for (int m = 0; m < 4; ++m)
      #pragma unroll
      for (int n = 0; n < 2; ++n)
        acc[m][n] = __builtin_amdgcn_mfma_f32_16x16x32_bf16(av[m], bv[n], acc[m][n], 0,0,0);
    __syncthreads();
    buf ^= 1;
  }

  // ---------- epilogue1: h3 = relu(acc + b1(re rows)) -> H3 bf16 (swizzled) ----------
  STAGE_B(W2b, 0, 0);      // prefetch GEMM2 kt=0 under the epilogue
  #pragma unroll
  for (int m = 0; m < 4; ++m){
    #pragma unroll
    for (int n = 0; n < 2; ++n){
      int col = w8*32 + n*16 + cl;
      float badd = (m < 2) ? b1[col] : 0.f;
      #pragma unroll
      for (int q = 0; q < 4; ++q){
        int row = m*16 + cq*4 + q;
        float v = fmaxf(acc[m][n][q] + badd, 0.f);
        int s = (col >> 3) ^ (row & 7);
        H3[row*256 + s*8 + (col & 7)] = f2bf(v);
      }
    }
  }
  __syncthreads();

  // ---------- GEMM2: acc = H3(64x256) @ W2b^T ----------
  #pragma unroll
  for (int m = 0; m < 4; ++m)
    #pragma unroll
    for (int n = 0; n < 2; ++n)
      acc[m][n] = (f32x4){0.f,0.f,0.f,0.f};

  buf = 0;
  for (int kt = 0; kt < 8; ++kt){
    if (kt < 7) STAGE_B(W2b, kt+1, buf^1);
    const ushort_t* Bb = (const ushort_t*)(lds + buf*16384);
    short8b av[4], bv[2];
    #pragma unroll
    for (int m = 0; m < 4; ++m){
      int r = m*16 + L;
      int s = (kt*4 + chk) ^ (r & 7);
      av[m] = *(const short8b*)&H3[r*256 + s*8];
    }
    #pragma unroll
    for (int n = 0; n < 2; ++n) bv[n] = *(const short8b*)&Bb[bvix + n*512];
    #pragma unroll
    for (int m = 0; m < 4; ++m)
      #pragma unroll
      for (int n = 0; n < 2; ++n)
        acc[m][n] = __builtin_amdgcn_mfma_f32_16x16x32_bf16(av[m], bv[n], acc[m][n], 0,0,0);
    __syncthreads();
    buf ^= 1;
  }

  // ---------- epilogue2: h4 packed bf16 -> Z[j][a][b] (j-stride ZJS) ----------
  #pragma unroll
  for (int m2 = 0; m2 < 2; ++m2){
    #pragma unroll
    for (int n = 0; n < 2; ++n){
      int col = w8*32 + n*16 + cl;
      float bias2 = b2[col];
      int a = col >> 4;                       // 2*w8 + n
      #pragma unroll
      for (int q = 0; q < 4; ++q){
        int j = m2*16 + cq*4 + q;
        Z[j*ZJS + a*16 + cl] = packf2(acc[m2][n][q] + bias2, acc[m2+2][n][q]);
      }
    }
  }
  __syncthreads();

  // ---------- v-IFFT stage 1: FFT16 over a, twiddle, in-place (column-private) ----------
  {
    const int j1 = tid >> 4;       // 0..31
    const int b1c = tid & 15;
    float sr[16], si[16];
    #pragma unroll
    for (int a = 0; a < 16; ++a){
      uint_t u = Z[j1*ZJS + a*16 + b1c];
      sr[a] = bf_lo(u); si[a] = bf_hi(u);
    }
    fft16_inv(sr, si);
    float2 ws = ph[b1c];
    float wr = 1.f/256.f, wi = 0.f;    // folds the 1/256 v-normalization
    #pragma unroll
    for (int d = 0; d < 16; ++d){
      float yr = sr[BR16T[d]], yi = si[BR16T[d]];
      Z[j1*ZJS + d*16 + b1c] = packf2(yr*wr - yi*wi, yr*wi + yi*wr);
      float nw = wr*ws.x - wi*ws.y;
      wi = wr*ws.y + wi*ws.x; wr = nw;
    }
  }
  __syncthreads();

  // ---------- v-IFFT stage 2: FFT16 over b, store packed planes ----------
  {
    const int j2 = tid >> 4;
    const int d2 = tid & 15;
    float br[16], bi[16];
    const uint4* zb = (const uint4*)&Z[j2*ZJS + d2*16];
    #pragma unroll
    for (int c = 0; c < 4; ++c){
      uint4 u4 = zb[c];
      br[c*4+0] = bf_lo(u4.x); bi[c*4+0] = bf_hi(u4.x);
      br[c*4+1] = bf_lo(u4.y); bi[c*4+1] = bf_hi(u4.y);
      br[c*4+2] = bf_lo(u4.z); bi[c*4+2] = bf_hi(u4.z);
      br[c*4+3] = bf_lo(u4.w); bi[c*4+3] = bf_hi(u4.w);
    }
    fft16_inv(br, bi);
    const long rowbase = (long)(cr0 + j2) * 256;
    #pragma unroll
    for (int p = 0; p < 16; ++p)
      OutP[rowbase + BR16T[p]*16 + d2] = packf2(br[p], bi[p]);
  }
  #undef STAGE_B
  #undef STAGE_A
}

// ---------------- m-axis IFFT: 16x16 four-step, in-place, 256 thr, uint2 (v-pairs) ----------------
__global__ __launch_bounds__(256)
void fft_m(uint_t* __restrict__ P, const float2* __restrict__ ph){
  __shared__ __align__(16) uint_t Z[16*546];   // [d (stride 546)][bm (stride 34)][32 v] ~34.9KB
  const int tid = threadIdx.x;
  const int p   = tid & 15;            // v-pair index: v = vg + 2p, 2p+1
  const int bm  = tid >> 4;            // 0..15
  const int bB  = blockIdx.x >> 3;     // batch 0..511
  const int vg  = (blockIdx.x & 7) << 5;
  const long base = (long)bB*65536 + vg + 2*p;

  float xr0[16], xi0[16], xr1[16], xi1[16];
  #pragma unroll
  for (int a = 0; a < 16; ++a){
    uint2 u = *(const uint2*)&P[base + (long)(a*16 + bm)*256];
    xr0[a] = bf_lo(u.x); xi0[a] = bf_hi(u.x);
    xr1[a] = bf_lo(u.y); xi1[a] = bf_hi(u.y);
  }
  fft16_inv(xr0, xi0);
  fft16_inv(xr1, xi1);
  float2 ws = ph[bm];
  float wr = 1.f/256.f, wi = 0.f;      // folds 1/256
  #pragma unroll
  for (int d = 0; d < 16; ++d){
    int s = BR16T[d];
    float ar0 = xr0[s], ai0 = xi0[s], ar1 = xr1[s], ai1 = xi1[s];
    *(uint2*)&Z[d*546 + bm*34 + 2*p] = make_uint2(
        packf2(ar0*wr - ai0*wi, ar0*wi + ai0*wr),
        packf2(ar1*wr - ai1*wi, ar1*wi + ai1*wr));
    float nw = wr*ws.x - wi*ws.y; wi = wr*ws.y + wi*ws.x; wr = nw;
  }
  __syncthreads();
  const int d2 = tid >> 4;
  float br0[16], bi0[16], br1[16], bi1[16];
  #pragma unroll
  for (int bb = 0; bb < 16; ++bb){
    uint2 u = *(const uint2*)&Z[d2*546 + bb*34 + 2*p];
    br0[bb] = bf_lo(u.x); bi0[bb] = bf_hi(u.x);
    br1[bb] = bf_lo(u.y); bi1[bb] = bf_hi(u.y);
  }
  fft16_inv(br0, bi0);
  fft16_inv(br1, bi1);
  #pragma unroll
  for (int q = 0; q < 16; ++q){
    int k = BR16T[q]*16 + d2;
    *(uint2*)&P[base + (long)k*256] =
        make_uint2(packf2(br0[q], bi0[q]), packf2(br1[q], bi1[q]));
  }
}

// ---------------- b-axis IFFT: 32x16 four-step, in-place, REAL fp32 out, 512 thr x 32 v ----------------
__global__ __launch_bounds__(512)
void fft_b(uint_t* __restrict__ P, const float2* __restrict__ t512){
  __shared__ uint_t Z[16384];          // [32 d][16 b][32 v] = 64KB, unpadded
  const int tid = threadIdx.x;
  const int v  = tid & 31;
  const int bq = tid >> 5;             // 0..15
  const int m  = blockIdx.x >> 3;      // 0..255
  const int vg = (blockIdx.x & 7) << 5;
  const long base = (long)m*256 + vg + v;

  float xr[32], xi[32];
  #pragma unroll
  for (int a = 0; a < 32; ++a){
    uint_t u = P[base + (long)(a*16 + bq)*65536];
    xr[a] = bf_lo(u); xi[a] = bf_hi(u);
  }
  fft32_inv(xr, xi);
  float2 ws = t512[bq];
  float wr = 1.f/512.f, wi = 0.f;      // folds 1/512
  #pragma unroll
  for (int d = 0; d < 32; ++d){
    float yr = xr[BR32T[d]], yi = xi[BR32T[d]];
    Z[d*512 + bq*32 + v] = packf2(yr*wr - yi*wi, yr*wi + yi*wr);
    float nw = wr*ws.x - wi*ws.y; wi = wr*ws.y + wi*ws.x; wr = nw;
  }
  __syncthreads();
  float* out = (float*)P;
  #pragma unroll
  for (int h = 0; h < 2; ++h){
    const int d = (tid >> 5) + 16*h;
    float br[16], bi[16];
    #pragma unroll
    for (int bb = 0; bb < 16; ++bb){
      uint_t u = Z[d*512 + bb*32 + v];
      br[bb] = bf_lo(u); bi[bb] = bf_hi(u);
    }
    fft16_inv(br, bi);
    #pragma unroll
    for (int p = 0; p < 16; ++p)
      out[base + (long)(BR16T[p]*32 + d)*65536] = br[p];
  }
}

// ---------------- launch ----------------
extern "C" void kernel_launch(void* const* d_in, const int* in_sizes, int n_in,
                              void* d_out, int out_size, void* d_ws, size_t ws_size,
                              hipStream_t stream) {
  (void)in_sizes; (void)n_in; (void)out_size; (void)ws_size;
  const float* x      = (const float*)d_in[0];
  const float* w0     = (const float*)d_in[1];
  const float* w1     = (const float*)d_in[2];
  const float* lin1_w = (const float*)d_in[3];
  const float* lin1_b = (const float*)d_in[4];
  const float* lin2_w = (const float*)d_in[5];
  const float* lin2_b = (const float*)d_in[6];

  // ws smalls only (~2.5 MB)
  char* sm = (char*)d_ws;
  float2*   Yw     = (float2*)sm;   sm += 1048576;
  float*    Xr     = (float*)sm;    sm += 524288;
  float*    Xi     = (float*)sm;    sm += 524288;
  float2*   t256f  = (float2*)sm;   sm += 2048;
  float2*   t256i  = (float2*)sm;   sm += 2048;
  float2*   t512f  = (float2*)sm;   sm += 4096;
  float2*   t512i  = (float2*)sm;   sm += 4096;
  ushort_t* Wct    = (ushort_t*)sm; sm += 131072;
  ushort_t* W2b    = (ushort_t*)sm; sm += 131072;

  uint_t* planes = (uint_t*)d_out;    // packed bf16 complex planes, 134 MB

  fill_tables<<<1, 512, 0, stream>>>(t256f, t256i, t512f, t512i);
  dft_m<<<512, 256, 0, stream>>>(x, Yw, t256f);
  dft_b<<<512, 256, 0, stream>>>(Yw, Xr, Xi, t512f);
  prep_w<<<256, 256, 0, stream>>>(w1, lin1_w, lin2_w, Wct, W2b);
  fused_mid<<<4096, 512, 0, stream>>>(Xr, Xi, w0, Wct, W2b, lin1_b, lin2_b,
                                      t256i, planes);
  fft_m<<<4096, 256, 0, stream>>>(planes, t256i);
  fft_b<<<2048, 512, 0, stream>>>(planes, t512i);
}